// Round 10
// baseline (160.289 us; speedup 1.0000x reference)
//
#include <hip/hip_runtime.h>
#include <stdint.h>

#define M_ROWS 12608   // 64 * 197
#define K_DIM  768
#define RANK   192
#define BM     64
#define BK     32
#define NKT    (K_DIM / BK)   // 24

typedef __attribute__((ext_vector_type(8))) short  short8;
typedef __attribute__((ext_vector_type(4))) float  float4v;

static __device__ __forceinline__ unsigned short f2bf(float f) {
    union { float f; uint32_t u; } v; v.f = f;
    uint32_t u = v.u;
    uint32_t r = u + 0x7FFFu + ((u >> 16) & 1u);   // round-to-nearest-even
    return (unsigned short)(r >> 16);
}

// Raw barrier WITHOUT vmcnt drain: LDS ops drained, global loads in flight.
#define SYNC_LDS()  do {                                        \
    asm volatile("s_waitcnt lgkmcnt(0)" ::: "memory");          \
    __builtin_amdgcn_s_barrier();                               \
    __builtin_amdgcn_sched_barrier(0);                          \
} while (0)

// ---------------------------------------------------------------------------
// Kernel 1: W [768][192] fp32 (x3 chunks) -> Wt [576][768] bf16 (transposed)
// ---------------------------------------------------------------------------
__global__ void convW_kernel(const float* __restrict__ wq, const float* __restrict__ wk,
                             const float* __restrict__ wv, unsigned short* __restrict__ Wt) {
    __shared__ float tile[32][33];
    const int ch = blockIdx.z;
    const float* w = (ch == 0) ? wq : (ch == 1) ? wk : wv;
    const int k0 = blockIdx.x * 32;
    const int r0 = blockIdx.y * 32;
    const int tj = threadIdx.x & 31;
    const int ti = threadIdx.x >> 5;   // 0..7
#pragma unroll
    for (int p = 0; p < 4; ++p) {
        int i = ti + p * 8;
        tile[i][tj] = w[(size_t)(k0 + i) * RANK + r0 + tj];   // coalesced in r
    }
    __syncthreads();
#pragma unroll
    for (int p = 0; p < 4; ++p) {
        int i = ti + p * 8;                                    // r-offset
        Wt[(size_t)(ch * RANK + r0 + i) * K_DIM + k0 + tj] = f2bf(tile[tj][i]); // coalesced in k
    }
}

// ---------------------------------------------------------------------------
// Kernel 2: out[ch][m][r] = gelu( X[m][:] . Wt[ch*192+r][:] )
// Round-10 re-tile targeting LDS-read volume + residency tail:
//   256 thr = 4 waves (1M x 4N), wave tile 64x48 (acc[4][3]): 7 ds_read_b128
//   per 12 MFMA (was 10/12) -> LDS reads -32%.
//   BK=32 -> LDS 32 KB dbuf -> whole 591-block grid co-resident (no 79-block
//   tail round). 64-B LDS rows, swizzle ((row>>1)&3)<<4 -> 2-way (free).
// Kept (validated): XCD map (FETCH 63->23 MB), nt stores (WRITE exact),
// raw lgkmcnt-only barrier.
// ---------------------------------------------------------------------------
__global__ __launch_bounds__(256, 4) void gemm_gelu_kernel(
        const float* __restrict__ X, const unsigned short* __restrict__ Wt,
        float* __restrict__ out) {
    const int id    = blockIdx.x;              // 0..599
    const int j     = id >> 3;                 // 0..74
    const int ch    = j % 3;                   // chunk
    const int mtile = (id & 7) + 8 * (j / 3);  // 0..199
    if (mtile >= 197) return;

    __shared__ unsigned short Al[2][BM * BK];     // 4 KB each
    __shared__ unsigned short Bl[2][RANK * BK];   // 12 KB each

    const int tid  = threadIdx.x;
    const int lane = tid & 63;
    const int wid  = tid >> 6;      // 0..3 = wn

    // ---- A staging: 256 chunks of 8 fp32 -> 16B bf16; thread t -> chunk t ----
    const int a_row   = tid >> 2;                      // 0..63
    const int a_kc    = tid & 3;                       // 0..3
    const size_t a_gb = (size_t)(mtile * BM + a_row) * K_DIM + a_kc * 8;
    const int a_laddr = a_row * 64 + ((a_kc * 16) ^ (((a_row >> 1) & 3) << 4));

    // ---- B staging: 768 chunks of 8 bf16 (16B); thread t -> t, t+256, t+512 ----
    int b_laddr[3];
    size_t b_gb[3];
#pragma unroll
    for (int i = 0; i < 3; ++i) {
        int c   = tid + i * 256;
        int row = c >> 2;                              // 0..191 (n-local)
        int kc  = c & 3;
        b_laddr[i] = row * 64 + ((kc * 16) ^ (((row >> 1) & 3) << 4));
        b_gb[i]    = (size_t)(ch * RANK + row) * K_DIM + kc * 8;
    }

    float4v rA0, rA1;
    int4 rB[3];

    auto LOADA = [&](int kt) {
        const float* p = X + a_gb + (size_t)kt * BK;
        rA0 = *reinterpret_cast<const float4v*>(p);
        rA1 = *reinterpret_cast<const float4v*>(p + 4);
    };
    auto LOADB = [&](int kt) {
#pragma unroll
        for (int i = 0; i < 3; ++i)
            rB[i] = *reinterpret_cast<const int4*>(Wt + b_gb[i] + (size_t)kt * BK);
    };
    auto WRITEBUF = [&](int buf) {
        uint32_t w0 = (uint32_t)f2bf(rA0[0]) | ((uint32_t)f2bf(rA0[1]) << 16);
        uint32_t w1 = (uint32_t)f2bf(rA0[2]) | ((uint32_t)f2bf(rA0[3]) << 16);
        uint32_t w2 = (uint32_t)f2bf(rA1[0]) | ((uint32_t)f2bf(rA1[1]) << 16);
        uint32_t w3 = (uint32_t)f2bf(rA1[2]) | ((uint32_t)f2bf(rA1[3]) << 16);
        int4 aw; aw.x = (int)w0; aw.y = (int)w1; aw.z = (int)w2; aw.w = (int)w3;
        *reinterpret_cast<int4*>(reinterpret_cast<char*>(&Al[buf][0]) + a_laddr) = aw;
        char* bb = reinterpret_cast<char*>(&Bl[buf][0]);
#pragma unroll
        for (int i = 0; i < 3; ++i)
            *reinterpret_cast<int4*>(bb + b_laddr[i]) = rB[i];
    };

    float4v acc[4][3];
#pragma unroll
    for (int mf = 0; mf < 4; ++mf)
#pragma unroll
        for (int nf = 0; nf < 3; ++nf)
            acc[mf][nf] = (float4v)(0.0f);

    const int kb = (lane >> 4) * 16;   // this lane's 16-B k-slot in a 64-B row
    auto COMPUTE = [&](int buf) {
        const char* ab = reinterpret_cast<const char*>(&Al[buf][0]);
        const char* bb = reinterpret_cast<const char*>(&Bl[buf][0]);
        short8 afr[4], bfr[3];
#pragma unroll
        for (int mf = 0; mf < 4; ++mf) {
            int row = mf * 16 + (lane & 15);
            afr[mf] = *reinterpret_cast<const short8*>(ab + row * 64 + (kb ^ (((row >> 1) & 3) << 4)));
        }
#pragma unroll
        for (int nf = 0; nf < 3; ++nf) {
            int row = wid * 48 + nf * 16 + (lane & 15);
            bfr[nf] = *reinterpret_cast<const short8*>(bb + row * 64 + (kb ^ (((row >> 1) & 3) << 4)));
        }
#pragma unroll
        for (int mf = 0; mf < 4; ++mf)
#pragma unroll
            for (int nf = 0; nf < 3; ++nf)
                acc[mf][nf] = __builtin_amdgcn_mfma_f32_16x16x32_bf16(
                    afr[mf], bfr[nf], acc[mf][nf], 0, 0, 0);
    };

    // ---- prologue: buf0 = tile 0; regs = tile 1 ----
    LOADA(0); LOADB(0);
    WRITEBUF(0);
    LOADA(1); LOADB(1);
    SYNC_LDS();

    // ---- K-loop ----
    for (int kt = 0; kt < NKT; ++kt) {
        const int cur = kt & 1;
        COMPUTE(cur);                                         // reads tile kt
        if (kt + 1 < NKT) WRITEBUF(cur ^ 1);                  // stage tile kt+1
        if (kt + 2 < NKT) { LOADA(kt + 2); LOADB(kt + 2); }   // prefetch kt+2
        if (kt + 1 < NKT) SYNC_LDS();                         // loads stay in flight
    }

    // ---- epilogue: exact gelu, fp32 NONTEMPORAL store ----
    const float inv_sqrt2 = 0.70710678118654752f;
    const size_t obase = (size_t)ch * ((size_t)M_ROWS * RANK);
#pragma unroll
    for (int mf = 0; mf < 4; ++mf) {
        const int mrow0 = mtile * BM + mf * 16 + ((lane >> 4) << 2);
#pragma unroll
        for (int nf = 0; nf < 3; ++nf) {
            const int ncol = wid * 48 + nf * 16 + (lane & 15);
#pragma unroll
            for (int r = 0; r < 4; ++r) {
                float x = acc[mf][nf][r];
                float g = 0.5f * x * (1.0f + erff(x * inv_sqrt2));
                __builtin_nontemporal_store(g, &out[obase + (size_t)(mrow0 + r) * RANK + ncol]);
            }
        }
    }
}

// ---------------------------------------------------------------------------
extern "C" void kernel_launch(void* const* d_in, const int* in_sizes, int n_in,
                              void* d_out, int out_size, void* d_ws, size_t ws_size,
                              hipStream_t stream) {
    const float* X  = (const float*)d_in[0];
    const float* wq = (const float*)d_in[1];
    const float* wk = (const float*)d_in[2];
    const float* wv = (const float*)d_in[3];
    unsigned short* Wt = (unsigned short*)d_ws;   // 576*768*2 = 884,736 B
    float* out = (float*)d_out;

    convW_kernel<<<dim3(24, 6, 3), 256, 0, stream>>>(wq, wk, wv, Wt);
    gemm_gelu_kernel<<<dim3(600), 256, 0, stream>>>(X, Wt, out);
}